// Round 7
// baseline (25112.459 us; speedup 1.0000x reference)
//
#include <hip/hip_runtime.h>
#include <math.h>
#include <stdint.h>

// MGU RNN, T=8192, IN=128, H=1024, L=3 — pipelined persistent kernel, R7.
// Skeleton = R6 (passed, 23.2ms best): 192 WGs = 3 layer-groups x 64 WGs,
// 512 threads (8 waves); wave a owns units jb=16r+2a, jb+1; all weights in
// VGPRs/AGPRs (128 floats/thread); tagged (tag<<32|float) u64 words through
// MALL via relaxed agent atomics; parity-2 h rows; 128-row x rings.
// R7 changes (R6 counters: 2.8x dispatch variance + 1.7GB poll fetches =
// MALL contention + power throttle from 98K threads spinning full-rate):
//  - pair ownership: thread polls adjacent words {2tid, 2tid+1} with ONE
//    global_load_dwordx4 sc0 sc1 (2 tagged words/instruction, 2x fewer ops;
//    each aligned 8B half validated by its own tag — no tearing hazard).
//  - s_sleep(1) backoff after each failed sweep (issue-rate down ~8x).
//  - x polled before h (ring producer runs ahead -> x hits on sweep 1;
//    h is the real critical wait).

#define T_STEPS 8192
#define HDIM 1024
#define RING 128

typedef unsigned long long u64;
typedef int v4i __attribute__((ext_vector_type(4)));

__device__ __forceinline__ u64 agload64(const u64* p) {
    return __hip_atomic_load(p, __ATOMIC_RELAXED, __HIP_MEMORY_SCOPE_AGENT);
}
__device__ __forceinline__ void agstore64(u64* p, u64 v) {
    __hip_atomic_store(p, v, __ATOMIC_RELAXED, __HIP_MEMORY_SCOPE_AGENT);
}
__device__ __forceinline__ int agloadi(const int* p) {
    return __hip_atomic_load(p, __ATOMIC_RELAXED, __HIP_MEMORY_SCOPE_AGENT);
}
__device__ __forceinline__ void agstorei(int* p, int v) {
    __hip_atomic_store(p, v, __ATOMIC_RELAXED, __HIP_MEMORY_SCOPE_AGENT);
}
// Coherent 16B poll: two adjacent tagged u64 words in one L2-bypassing load.
// Little-endian: .x=float0 bits, .y=tag0, .z=float1 bits, .w=tag1.
__device__ __forceinline__ v4i poll16(const u64* p) {
    v4i r;
    asm volatile("global_load_dwordx4 %0, %1, off sc0 sc1\n\t"
                 "s_waitcnt vmcnt(0)"
                 : "=v"(r) : "v"(p) : "memory");
    return r;
}
__device__ __forceinline__ float dot4(float4 a, float4 b) {
    return a.x * b.x + a.y * b.y + a.z * b.z + a.w * b.w;
}
__device__ __forceinline__ u64 pack(float v, int tag) {
    return ((u64)(unsigned)tag << 32) | (u64)__float_as_uint(v);
}
__device__ __forceinline__ void opaque4(float4& v) {
    asm volatile("" : "+v"(v.x), "+v"(v.y), "+v"(v.z), "+v"(v.w));
}
__device__ __forceinline__ void opaque2(float2& v) {
    asm volatile("" : "+v"(v.x), "+v"(v.y));
}

// K: input width. L: layer index 0..2.
template <int K, int L>
__device__ void scan_layer(float* __restrict__ s_h,   // LDS [2][HDIM]
                           float* __restrict__ s_x,   // LDS [2][HDIM]
                           const float* __restrict__ S,         // L==0
                           const u64*  __restrict__ xring_in,   // L>0
                           u64*        __restrict__ xring_out,  // L<2
                           float*      __restrict__ xout,       // L==2
                           const float* __restrict__ h0,
                           const float* __restrict__ w_ih,
                           const float* __restrict__ b_ih,
                           const float* __restrict__ w_hh,
                           const float* __restrict__ b_hh,
                           u64* __restrict__ htag,              // [2,H]
                           int* __restrict__ progNext,          // L<2
                           int* __restrict__ progSelf,          // L>0
                           int r)
{
    const int tid = threadIdx.x;       // 0..511
    const int a   = tid >> 6;          // wave 0..7
    const int q   = tid & 63;          // lane
    const int jb  = r * 16 + 2 * a;    // wave owns units jb, jb+1

    // ---- weights -> VGPRs/AGPRs (128 floats/thread), pinned opaque ----
    float4 wf[2][4], wn[2][4];
#pragma unroll
    for (int g = 0; g < 2; ++g) {
        const float* rf = w_hh + (size_t)(jb + g) * HDIM;
        const float* rn = w_hh + (size_t)(HDIM + jb + g) * HDIM;
#pragma unroll
        for (int m = 0; m < 4; ++m) {
            wf[g][m] = *(const float4*)(rf + 4 * q + 256 * m);
            wn[g][m] = *(const float4*)(rn + 4 * q + 256 * m);
            opaque4(wf[g][m]); opaque4(wn[g][m]);
        }
    }
    float4 wif[2][4], win[2][4];   // K==1024
    float2 wif2[2], win2[2];       // K==128
    if constexpr (K == 1024) {
#pragma unroll
        for (int g = 0; g < 2; ++g) {
            const float* rf = w_ih + (size_t)(jb + g) * K;
            const float* rn = w_ih + (size_t)(HDIM + jb + g) * K;
#pragma unroll
            for (int m = 0; m < 4; ++m) {
                wif[g][m] = *(const float4*)(rf + 4 * q + 256 * m);
                win[g][m] = *(const float4*)(rn + 4 * q + 256 * m);
                opaque4(wif[g][m]); opaque4(win[g][m]);
            }
        }
    } else {
#pragma unroll
        for (int g = 0; g < 2; ++g) {
            wif2[g] = *(const float2*)(w_ih + (size_t)(jb + g) * K + 2 * q);
            win2[g] = *(const float2*)(w_ih + (size_t)(HDIM + jb + g) * K + 2 * q);
            opaque2(wif2[g]); opaque2(win2[g]);
        }
    }
    float bFv[2], bInv[2], bHnv[2];
#pragma unroll
    for (int g = 0; g < 2; ++g) {
        bFv[g]  = b_ih[jb + g] + b_hh[jb + g];
        bInv[g] = b_ih[HDIM + jb + g];
        bHnv[g] = b_hh[HDIM + jb + g];
    }

    int lastProg = 0;
    for (int t = 0; t < T_STEPS; ++t) {
        const int par = t & 1;
        const u64* hrow = htag + (size_t)((t + 1) & 1) * HDIM;  // parity of t-1
        u64*       hpub = htag + (size_t)par * HDIM;
        float* hD = s_h + par * HDIM;
        float* xD = s_x + par * HDIM;

        // ---- amortized ring backpressure (off critical path) ----
        if constexpr (L < 2) {
            if (t - lastProg > RING - 16) {
                do { lastProg = agloadi(progNext); } while (t - lastProg > RING - 16);
            }
        }

        // ---- poll own pair of x words first (producer runs ahead) ----
        if constexpr (L > 0) {
            const u64* xrow = xring_in + (size_t)(t & (RING - 1)) * HDIM;
            const unsigned xe = (unsigned)(t + 1);
            for (;;) {
                const v4i v = poll16(xrow + 2 * tid);
                if ((unsigned)v.y == xe && (unsigned)v.w == xe) {
                    ((float2*)xD)[tid] =
                        make_float2(__int_as_float(v.x), __int_as_float(v.z));
                    break;
                }
                __builtin_amdgcn_s_sleep(1);
            }
        } else {
            if (tid < K / 4)
                ((float4*)xD)[tid] = ((const float4*)(S + (size_t)t * K))[tid];
        }

        // ---- poll own pair of h words (the critical wait) ----
        if (t == 0) {
            ((float2*)hD)[tid] = ((const float2*)h0)[tid];
        } else {
            const unsigned he = (unsigned)t;
            for (;;) {
                const v4i v = poll16(hrow + 2 * tid);
                if ((unsigned)v.y == he && (unsigned)v.w == he) {
                    ((float2*)hD)[tid] =
                        make_float2(__int_as_float(v.x), __int_as_float(v.z));
                    break;
                }
                __builtin_amdgcn_s_sleep(1);
            }
        }
        __syncthreads();   // the ONE barrier per step

        // consumer progress: barrier proved ALL waves read x_t from global
        if constexpr (L > 0) {
            if (r == 0 && tid == 0) agstorei(progSelf, t + 1);
        }

        // ---- dots for units jb, jb+1 (conflict-free b128 LDS reads) ----
        float aF[2]  = {0.f, 0.f};
        float aNh[2] = {0.f, 0.f};
        float aNi[2] = {0.f, 0.f};
#pragma unroll
        for (int m = 0; m < 4; ++m) {
            const float4 h4 = ((const float4*)hD)[q + 64 * m];
#pragma unroll
            for (int g = 0; g < 2; ++g) {
                aF[g]  += dot4(wf[g][m], h4);
                aNh[g] += dot4(wn[g][m], h4);
            }
        }
        if constexpr (K == 1024) {
#pragma unroll
            for (int m = 0; m < 4; ++m) {
                const float4 x4 = ((const float4*)xD)[q + 64 * m];
#pragma unroll
                for (int g = 0; g < 2; ++g) {
                    aF[g]  += dot4(wif[g][m], x4);
                    aNi[g] += dot4(win[g][m], x4);
                }
            }
        } else {
            const float2 x2 = *(const float2*)&xD[2 * q];
#pragma unroll
            for (int g = 0; g < 2; ++g) {
                aF[g]  += wif2[g].x * x2.x + wif2[g].y * x2.y;
                aNi[g] += win2[g].x * x2.x + win2[g].y * x2.y;
            }
        }

        // ---- two-phase reduction: pair butterfly, select, stride butterfly
#pragma unroll
        for (int g = 0; g < 2; ++g) {
            aF[g]  += __shfl_xor(aF[g],  1, 64);
            aNh[g] += __shfl_xor(aNh[g], 1, 64);
            aNi[g] += __shfl_xor(aNi[g], 1, 64);
        }
        const int gs = q & 1;
        float vF  = gs ? aF[1]  : aF[0];
        float vNh = gs ? aNh[1] : aNh[0];
        float vNi = gs ? aNi[1] : aNi[0];
#pragma unroll
        for (int off = 2; off <= 32; off <<= 1) {
            vF  += __shfl_xor(vF,  off, 64);
            vNh += __shfl_xor(vNh, off, 64);
            vNi += __shfl_xor(vNi, off, 64);
        }

        // ---- gate + publish: lane 0 -> unit jb, lane 1 -> unit jb+1 ----
        if (q < 2) {
            const float cF  = gs ? bFv[1]  : bFv[0];
            const float cIn = gs ? bInv[1] : bInv[0];
            const float cHn = gs ? bHnv[1] : bHnv[0];
            const int   j   = jb + q;
            const float hp  = hD[j];
            const float f   = 1.f / (1.f + expf(-(vF + cF)));
            const float n   = tanhf(vNi + cIn + f * (vNh + cHn));
            const float hy  = n + (1.f - f) * (hp - n);
            const u64   pk  = pack(hy, t + 1);
            agstore64(hpub + j, pk);
            if constexpr (L < 2) {
                agstore64(xring_out + (size_t)(t & (RING - 1)) * HDIM + j, pk);
            } else {
                xout[(size_t)t * HDIM + j] = hy;
            }
        }
        // no trailing barrier: parity LDS buffers + per-step barrier bound
        // intra-WG skew to 1 step.
    }
}

__global__ __launch_bounds__(512, 2)
void mgu_pipe(const float* __restrict__ S,
              const float* __restrict__ h0,
              const float* __restrict__ w_ih0, const float* __restrict__ b_ih0,
              const float* __restrict__ w_hh0, const float* __restrict__ b_hh0,
              const float* __restrict__ w_ih_r, const float* __restrict__ b_ih_r,
              const float* __restrict__ w_hh_r, const float* __restrict__ b_hh_r,
              float* __restrict__ xbuf2, u64* __restrict__ ring0,
              u64* __restrict__ ring1, u64* __restrict__ htag,
              int* __restrict__ prog)
{
    __shared__ __align__(16) float s_h[2 * HDIM];
    __shared__ __align__(16) float s_x[2 * HDIM];
    const int grp = blockIdx.x >> 6;
    const int r   = blockIdx.x & 63;
    if (grp == 0) {
        scan_layer<128, 0>(s_h, s_x, S, nullptr, ring0, nullptr, h0,
                           w_ih0, b_ih0, w_hh0, b_hh0,
                           htag, prog + 1, nullptr, r);
    } else if (grp == 1) {
        scan_layer<1024, 1>(s_h, s_x, nullptr, ring0, ring1, nullptr, h0 + HDIM,
                            w_ih_r, b_ih_r, w_hh_r, b_hh_r,
                            htag + 2 * HDIM, prog + 2, prog + 1, r);
    } else {
        scan_layer<1024, 2>(s_h, s_x, nullptr, ring1, nullptr, xbuf2,
                            h0 + 2 * HDIM,
                            w_ih_r + 2048 * 1024, b_ih_r + 2048,
                            w_hh_r + 2048 * 1024, b_hh_r + 2048,
                            htag + 4 * HDIM, nullptr, prog + 2, r);
    }
}

__global__ __launch_bounds__(256)
void mgu_out(const float* __restrict__ x,       // [T, H]
             const float* __restrict__ w_out,   // [1, H]
             const float* __restrict__ b_out,   // [1]
             float* __restrict__ out)           // [T]
{
    const int wave = threadIdx.x >> 6;
    const int lane = threadIdx.x & 63;
    const int t = blockIdx.x * 4 + wave;
    float acc = 0.f;
#pragma unroll
    for (int m = 0; m < 4; ++m) {
        const int i4 = lane + 64 * m;
        const float4 x4 = ((const float4*)(x + (size_t)t * HDIM))[i4];
        const float4 w4 = ((const float4*)w_out)[i4];
        acc += dot4(x4, w4);
    }
#pragma unroll
    for (int off = 32; off > 0; off >>= 1) acc += __shfl_xor(acc, off, 64);
    if (lane == 0) out[t] = acc + b_out[0];
}

extern "C" void kernel_launch(void* const* d_in, const int* in_sizes, int n_in,
                              void* d_out, int out_size, void* d_ws, size_t ws_size,
                              hipStream_t stream) {
    const float* S      = (const float*)d_in[0];   // [8192,128]
    const float* h0     = (const float*)d_in[1];   // [3,1024]
    const float* w_ih0  = (const float*)d_in[2];   // [2048,128]
    const float* w_hh0  = (const float*)d_in[3];   // [2048,1024]
    const float* b_ih0  = (const float*)d_in[4];   // [2048]
    const float* b_hh0  = (const float*)d_in[5];   // [2048]
    const float* w_ih_r = (const float*)d_in[6];   // [2,2048,1024]
    const float* w_hh_r = (const float*)d_in[7];   // [2,2048,1024]
    const float* b_ih_r = (const float*)d_in[8];   // [2,2048]
    const float* b_hh_r = (const float*)d_in[9];   // [2,2048]
    const float* w_out  = (const float*)d_in[10];  // [1,1024]
    const float* b_out  = (const float*)d_in[11];  // [1]
    float* out = (float*)d_out;                    // [8192]

    char* ws = (char*)d_ws;
    float* xbuf2 = (float*)(ws);                        // 32 MB  [T,H] f32
    u64*   ring0 = (u64*)(ws + (32u << 20));            // 1 MB   [RING,H] u64
    u64*   ring1 = (u64*)(ws + (33u << 20));            // 1 MB
    u64*   htag  = (u64*)(ws + (34u << 20));            // 3 x [2,H] u64
    int*   prog  = (int*)(ws + (34u << 20) + (64u << 10));

    // No init kernel: tags/progress use exact-match vs the 0xAA poison.
    mgu_pipe<<<192, 512, 0, stream>>>(S, h0, w_ih0, b_ih0, w_hh0, b_hh0,
                                      w_ih_r, b_ih_r, w_hh_r, b_hh_r,
                                      xbuf2, ring0, ring1, htag, prog);
    mgu_out<<<2048, 256, 0, stream>>>(xbuf2, w_out, b_out, out);
}